// Round 1
// baseline (7290.528 us; speedup 1.0000x reference)
//
#include <hip/hip_runtime.h>

// ---------------------------------------------------------------------------
// 3-layer GCN (DGL GraphConv norm='both') on MI355X.
// Round 0: correctness-first fp32 implementation.
//   deg -> rsqrt norms -> per layer: [scaled GEMM] -> [atomic scatter-add] ->
//   [in-norm scale (+ReLU)]
// ---------------------------------------------------------------------------

__global__ __launch_bounds__(256) void degree_kernel(
    const int* __restrict__ src, const int* __restrict__ dst,
    float* __restrict__ deg_out, float* __restrict__ deg_in, int E) {
    int e = blockIdx.x * 256 + threadIdx.x;
    if (e < E) {
        atomicAdd(&deg_out[src[e]], 1.0f);
        atomicAdd(&deg_in[dst[e]], 1.0f);
    }
}

__global__ __launch_bounds__(256) void invsqrt_kernel(
    const float* __restrict__ deg_out, const float* __restrict__ deg_in,
    float* __restrict__ iso, float* __restrict__ isi, int N) {
    int n = blockIdx.x * 256 + threadIdx.x;
    if (n < N) {
        float a = deg_out[n], b = deg_in[n];
        iso[n] = (a > 0.0f) ? rsqrtf(a) : 0.0f;
        isi[n] = (b > 0.0f) ? rsqrtf(b) : 0.0f;
    }
}

// Y[node, col] = sum_k (X[node,k] * so[node]) * W[k, col]
// Block: 256 threads. Each thread: 1 node x 8 consecutive cols.
// K tiled at 64 so W-tile LDS stays modest (F=128: 32KB W + 4.4KB X).
template <int F_OUT>
__global__ __launch_bounds__(256) void gemm_scaled(
    const float* __restrict__ X, const float* __restrict__ W,
    const float* __restrict__ so, float* __restrict__ Y, int N) {
    constexpr int TPN = F_OUT / 8;   // threads per node (16 or 8)
    constexpr int NPB = 256 / TPN;   // nodes per block  (16 or 32)
    constexpr int KT = 64;
    constexpr int K = 128;

    __shared__ float Wl[KT * F_OUT];
    __shared__ float Xl[NPB][KT + 4];  // +4 pad: distinct banks across nodes

    const int tid = threadIdx.x;
    const int node0 = blockIdx.x * NPB;
    const int col0 = (tid % TPN) * 8;
    const int nl = tid / TPN;

    float acc[8];
#pragma unroll
    for (int j = 0; j < 8; ++j) acc[j] = 0.0f;

    for (int k0 = 0; k0 < K; k0 += KT) {
        __syncthreads();
        // stage W tile [KT x F_OUT] (row-major, contiguous cols)
        const float4* Wg = reinterpret_cast<const float4*>(W + (size_t)k0 * F_OUT);
        float4* Wl4 = reinterpret_cast<float4*>(Wl);
        for (int i = tid; i < KT * F_OUT / 4; i += 256) Wl4[i] = Wg[i];
        // stage X tile [NPB x KT], scaled by out-norm
        for (int i = tid; i < NPB * KT / 4; i += 256) {
            int r = i / (KT / 4);
            int c4 = i % (KT / 4);
            int node = node0 + r;
            if (node >= N) node = N - 1;  // safe clamp (N divisible anyway)
            float4 v = reinterpret_cast<const float4*>(X + (size_t)node * K + k0)[c4];
            float s = so[node];
            v.x *= s; v.y *= s; v.z *= s; v.w *= s;
            *reinterpret_cast<float4*>(&Xl[r][c4 * 4]) = v;
        }
        __syncthreads();
#pragma unroll
        for (int k = 0; k < KT; ++k) {
            float xv = Xl[nl][k];
            const float4 w0 = *reinterpret_cast<const float4*>(&Wl[k * F_OUT + col0]);
            const float4 w1 = *reinterpret_cast<const float4*>(&Wl[k * F_OUT + col0 + 4]);
            acc[0] = fmaf(xv, w0.x, acc[0]);
            acc[1] = fmaf(xv, w0.y, acc[1]);
            acc[2] = fmaf(xv, w0.z, acc[2]);
            acc[3] = fmaf(xv, w0.w, acc[3]);
            acc[4] = fmaf(xv, w1.x, acc[4]);
            acc[5] = fmaf(xv, w1.y, acc[5]);
            acc[6] = fmaf(xv, w1.z, acc[6]);
            acc[7] = fmaf(xv, w1.w, acc[7]);
        }
    }

    int node = node0 + nl;
    if (node < N) {
        float4* Y4 = reinterpret_cast<float4*>(Y + (size_t)node * F_OUT + col0);
        Y4[0] = make_float4(acc[0], acc[1], acc[2], acc[3]);
        Y4[1] = make_float4(acc[4], acc[5], acc[6], acc[7]);
    }
}

// agg[dst[e], :] += msg[src[e], :] via fp32 atomics; one thread per (edge, 4 feats)
template <int F>
__global__ __launch_bounds__(256) void scatter_kernel(
    const float* __restrict__ msg, const int* __restrict__ src,
    const int* __restrict__ dst, float* __restrict__ agg, int E) {
    constexpr int F4 = F / 4;
    int idx = blockIdx.x * 256 + threadIdx.x;
    if (idx >= E * F4) return;
    int e = idx / F4;
    int f4 = idx % F4;
    int s = src[e];
    int d = dst[e];
    const float4 m = reinterpret_cast<const float4*>(msg)[(size_t)s * F4 + f4];
    float* p = agg + (size_t)d * F + f4 * 4;
    atomicAdd(p + 0, m.x);
    atomicAdd(p + 1, m.y);
    atomicAdd(p + 2, m.z);
    atomicAdd(p + 3, m.w);
}

template <int F, bool RELU>
__global__ __launch_bounds__(256) void scale_kernel(
    float* __restrict__ A, const float* __restrict__ isi, int N) {
    constexpr int F4 = F / 4;
    int idx = blockIdx.x * 256 + threadIdx.x;
    if (idx >= N * F4) return;
    int n = idx / F4;
    float s = isi[n];
    float4 v = reinterpret_cast<float4*>(A)[idx];
    v.x *= s; v.y *= s; v.z *= s; v.w *= s;
    if (RELU) {
        v.x = fmaxf(v.x, 0.0f);
        v.y = fmaxf(v.y, 0.0f);
        v.z = fmaxf(v.z, 0.0f);
        v.w = fmaxf(v.w, 0.0f);
    }
    reinterpret_cast<float4*>(A)[idx] = v;
}

extern "C" void kernel_launch(void* const* d_in, const int* in_sizes, int n_in,
                              void* d_out, int out_size, void* d_ws, size_t ws_size,
                              hipStream_t stream) {
    const float* features = (const float*)d_in[0];
    const float* W1 = (const float*)d_in[1];
    const float* W2 = (const float*)d_in[2];
    const float* W3 = (const float*)d_in[3];
    const int* src = (const int*)d_in[4];
    const int* dst = (const int*)d_in[5];
    float* out = (float*)d_out;

    const int N = in_sizes[0] / 128;  // 100000
    const int E = in_sizes[4];        // 1600000

    float* ws = (float*)d_ws;
    float* A = ws;                          // N x 128
    float* B = A + (size_t)N * 128;         // N x 128
    float* deg = B + (size_t)N * 128;       // 2N (deg_out, deg_in)
    float* deg_out_p = deg;
    float* deg_in_p = deg + N;
    float* iso = deg + 2 * (size_t)N;
    float* isi = deg + 3 * (size_t)N;

    // --- norms ---
    hipMemsetAsync(deg, 0, 2 * (size_t)N * sizeof(float), stream);
    degree_kernel<<<(E + 255) / 256, 256, 0, stream>>>(src, dst, deg_out_p, deg_in_p, E);
    invsqrt_kernel<<<(N + 255) / 256, 256, 0, stream>>>(deg_out_p, deg_in_p, iso, isi, N);

    const int g128 = (N + 15) / 16;   // gemm<128> grid
    const int g64 = (N + 31) / 32;    // gemm<64> grid
    const int s128 = (E * 32 + 255) / 256;
    const int s64 = (E * 16 + 255) / 256;
    const int c128 = (N * 32 + 255) / 256;
    const int c64 = (N * 16 + 255) / 256;

    // --- layer 1 ---
    gemm_scaled<128><<<g128, 256, 0, stream>>>(features, W1, iso, B, N);
    hipMemsetAsync(A, 0, (size_t)N * 128 * sizeof(float), stream);
    scatter_kernel<128><<<s128, 256, 0, stream>>>(B, src, dst, A, E);
    scale_kernel<128, true><<<c128, 256, 0, stream>>>(A, isi, N);

    // --- layer 2 ---
    gemm_scaled<128><<<g128, 256, 0, stream>>>(A, W2, iso, B, N);
    hipMemsetAsync(A, 0, (size_t)N * 128 * sizeof(float), stream);
    scatter_kernel<128><<<s128, 256, 0, stream>>>(B, src, dst, A, E);
    scale_kernel<128, true><<<c128, 256, 0, stream>>>(A, isi, N);

    // --- layer 3 (scatter straight into d_out) ---
    gemm_scaled<64><<<g64, 256, 0, stream>>>(A, W3, iso, B, N);
    hipMemsetAsync(out, 0, (size_t)N * 64 * sizeof(float), stream);
    scatter_kernel<64><<<s64, 256, 0, stream>>>(B, src, dst, out, E);
    scale_kernel<64, false><<<c64, 256, 0, stream>>>(out, isi, N);
}

// Round 2
// 1206.647 us; speedup vs baseline: 6.0420x; 6.0420x over previous
//
#include <hip/hip_runtime.h>

// ---------------------------------------------------------------------------
// 3-layer GCN (DGL GraphConv norm='both') on MI355X.
// Round 2: pull-based CSR aggregation (replaces fp32 atomic scatter which
// wrote 3.2 GB/layer to HBM). Per layer: scaled GEMM -> CSR gather+acc with
// fused in-norm scale (+ReLU).
// ---------------------------------------------------------------------------

__global__ __launch_bounds__(256) void count_kernel(
    const int* __restrict__ src, const int* __restrict__ dst,
    int* __restrict__ cnt_out, int* __restrict__ cnt_in, int E) {
    int e = blockIdx.x * 256 + threadIdx.x;
    if (e < E) {
        atomicAdd(&cnt_out[src[e]], 1);
        atomicAdd(&cnt_in[dst[e]], 1);
    }
}

__global__ __launch_bounds__(256) void invsqrt_kernel(
    const int* __restrict__ cnt_out, const int* __restrict__ cnt_in,
    float* __restrict__ iso, float* __restrict__ isi, int N) {
    int n = blockIdx.x * 256 + threadIdx.x;
    if (n < N) {
        float a = (float)cnt_out[n], b = (float)cnt_in[n];
        iso[n] = (a > 0.0f) ? rsqrtf(a) : 0.0f;
        isi[n] = (b > 0.0f) ? rsqrtf(b) : 0.0f;
    }
}

// Single-block exclusive scan of cnt[0..N) -> row_ptr[0..N]. 1024 threads,
// each handles a contiguous chunk; block-level Hillis-Steele over partials.
__global__ __launch_bounds__(1024) void scan_kernel(
    const int* __restrict__ cnt, int* __restrict__ row_ptr, int N) {
    __shared__ int sums[1024];
    const int tid = threadIdx.x;
    const int chunk = (N + 1023) / 1024;
    const int begin = tid * chunk;
    const int stop = min(begin + chunk, N);
    int s = 0;
    for (int i = begin; i < stop; ++i) s += cnt[i];
    sums[tid] = s;
    __syncthreads();
    for (int off = 1; off < 1024; off <<= 1) {
        int v = (tid >= off) ? sums[tid - off] : 0;
        __syncthreads();
        sums[tid] += v;
        __syncthreads();
    }
    int run = (tid > 0) ? sums[tid - 1] : 0;  // exclusive prefix of this chunk
    for (int i = begin; i < stop; ++i) {
        row_ptr[i] = run;
        run += cnt[i];
    }
    if (tid == 1023) row_ptr[N] = sums[1023];
}

__global__ __launch_bounds__(256) void fill_csr_kernel(
    const int* __restrict__ src, const int* __restrict__ dst,
    const int* __restrict__ row_ptr, int* __restrict__ cur,
    int* __restrict__ col, int E) {
    int e = blockIdx.x * 256 + threadIdx.x;
    if (e < E) {
        int d = dst[e];
        int p = row_ptr[d] + atomicAdd(&cur[d], 1);
        col[p] = src[e];
    }
}

// Y[node, c] = sum_k (X[node,k] * so[node]) * W[k, c]   (out-norm fused)
template <int F_OUT>
__global__ __launch_bounds__(256) void gemm_scaled(
    const float* __restrict__ X, const float* __restrict__ W,
    const float* __restrict__ so, float* __restrict__ Y, int N) {
    constexpr int TPN = F_OUT / 8;   // threads per node
    constexpr int NPB = 256 / TPN;   // nodes per block
    constexpr int KT = 64;
    constexpr int K = 128;

    __shared__ float Wl[KT * F_OUT];
    __shared__ float Xl[NPB][KT + 4];

    const int tid = threadIdx.x;
    const int node0 = blockIdx.x * NPB;
    const int col0 = (tid % TPN) * 8;
    const int nl = tid / TPN;

    float acc[8];
#pragma unroll
    for (int j = 0; j < 8; ++j) acc[j] = 0.0f;

    for (int k0 = 0; k0 < K; k0 += KT) {
        __syncthreads();
        const float4* Wg = reinterpret_cast<const float4*>(W + (size_t)k0 * F_OUT);
        float4* Wl4 = reinterpret_cast<float4*>(Wl);
        for (int i = tid; i < KT * F_OUT / 4; i += 256) Wl4[i] = Wg[i];
        for (int i = tid; i < NPB * KT / 4; i += 256) {
            int r = i / (KT / 4);
            int c4 = i % (KT / 4);
            int node = node0 + r;
            if (node >= N) node = N - 1;
            float4 v = reinterpret_cast<const float4*>(X + (size_t)node * K + k0)[c4];
            float s = so[node];
            v.x *= s; v.y *= s; v.z *= s; v.w *= s;
            *reinterpret_cast<float4*>(&Xl[r][c4 * 4]) = v;
        }
        __syncthreads();
#pragma unroll
        for (int k = 0; k < KT; ++k) {
            float xv = Xl[nl][k];
            const float4 w0 = *reinterpret_cast<const float4*>(&Wl[k * F_OUT + col0]);
            const float4 w1 = *reinterpret_cast<const float4*>(&Wl[k * F_OUT + col0 + 4]);
            acc[0] = fmaf(xv, w0.x, acc[0]);
            acc[1] = fmaf(xv, w0.y, acc[1]);
            acc[2] = fmaf(xv, w0.z, acc[2]);
            acc[3] = fmaf(xv, w0.w, acc[3]);
            acc[4] = fmaf(xv, w1.x, acc[4]);
            acc[5] = fmaf(xv, w1.y, acc[5]);
            acc[6] = fmaf(xv, w1.z, acc[6]);
            acc[7] = fmaf(xv, w1.w, acc[7]);
        }
    }

    int node = node0 + nl;
    if (node < N) {
        float4* Y4 = reinterpret_cast<float4*>(Y + (size_t)node * F_OUT + col0);
        Y4[0] = make_float4(acc[0], acc[1], acc[2], acc[3]);
        Y4[1] = make_float4(acc[4], acc[5], acc[6], acc[7]);
    }
}

// Pull aggregation: one wave per destination node. Lane l accumulates
// feature slots; epilogue applies in-norm (+ReLU). F=128 -> float2/lane,
// F=64 -> float/lane. Coalesced 512B/256B row reads, no atomics.
template <int F, bool RELU>
__global__ __launch_bounds__(256) void gather_agg(
    const float* __restrict__ msg, const int* __restrict__ row_ptr,
    const int* __restrict__ col, const float* __restrict__ isi,
    float* __restrict__ out, int N) {
    const int wave = (blockIdx.x * 256 + threadIdx.x) >> 6;
    const int lane = threadIdx.x & 63;
    if (wave >= N) return;
    const int start = row_ptr[wave];
    const int end = row_ptr[wave + 1];

    if (F == 128) {
        float a0 = 0.0f, a1 = 0.0f;
        for (int e = start; e < end; ++e) {
            const int s = col[e];  // wave-uniform -> broadcast
            const float2 v =
                reinterpret_cast<const float2*>(msg + (size_t)s * 128)[lane];
            a0 += v.x;
            a1 += v.y;
        }
        const float sc = isi[wave];
        a0 *= sc; a1 *= sc;
        if (RELU) { a0 = fmaxf(a0, 0.0f); a1 = fmaxf(a1, 0.0f); }
        reinterpret_cast<float2*>(out + (size_t)wave * 128)[lane] =
            make_float2(a0, a1);
    } else {
        float a0 = 0.0f;
        for (int e = start; e < end; ++e) {
            const int s = col[e];
            a0 += msg[(size_t)s * F + lane];
        }
        const float sc = isi[wave];
        a0 *= sc;
        if (RELU) a0 = fmaxf(a0, 0.0f);
        out[(size_t)wave * F + lane] = a0;
    }
}

extern "C" void kernel_launch(void* const* d_in, const int* in_sizes, int n_in,
                              void* d_out, int out_size, void* d_ws, size_t ws_size,
                              hipStream_t stream) {
    const float* features = (const float*)d_in[0];
    const float* W1 = (const float*)d_in[1];
    const float* W2 = (const float*)d_in[2];
    const float* W3 = (const float*)d_in[3];
    const int* src = (const int*)d_in[4];
    const int* dst = (const int*)d_in[5];
    float* out = (float*)d_out;

    const int N = in_sizes[0] / 128;  // 100000
    const int E = in_sizes[4];        // 1600000

    // Workspace layout (floats/ints interleaved; all 4-byte):
    char* ws = (char*)d_ws;
    float* A = (float*)ws;                       ws += (size_t)N * 128 * 4;
    float* B = (float*)ws;                       ws += (size_t)N * 128 * 4;
    int* cnt_out = (int*)ws;                     ws += (size_t)N * 4;
    int* cnt_in = (int*)ws;                      ws += (size_t)N * 4;
    int* row_ptr = (int*)ws;                     ws += (size_t)(N + 1) * 4;
    int* cur = (int*)ws;                         ws += (size_t)N * 4;
    int* col = (int*)ws;                         ws += (size_t)E * 4;
    float* iso = (float*)ws;                     ws += (size_t)N * 4;
    float* isi = (float*)ws;

    const int gE = (E + 255) / 256;
    const int gN = (N + 255) / 256;

    // --- norms + CSR build (per-call; deterministic work for graph capture) ---
    hipMemsetAsync(cnt_out, 0, 2 * (size_t)N * sizeof(int), stream);  // cnt_out+cnt_in
    count_kernel<<<gE, 256, 0, stream>>>(src, dst, cnt_out, cnt_in, E);
    invsqrt_kernel<<<gN, 256, 0, stream>>>(cnt_out, cnt_in, iso, isi, N);
    scan_kernel<<<1, 1024, 0, stream>>>(cnt_in, row_ptr, N);
    hipMemsetAsync(cur, 0, (size_t)N * sizeof(int), stream);
    fill_csr_kernel<<<gE, 256, 0, stream>>>(src, dst, row_ptr, cur, col, E);

    const int g128 = (N + 15) / 16;  // gemm<128> grid (16 nodes/block)
    const int g64 = (N + 31) / 32;   // gemm<64> grid  (32 nodes/block)
    const int ga = (N * 64 + 255) / 256;  // gather_agg grid: 1 wave/node

    // --- layer 1 ---
    gemm_scaled<128><<<g128, 256, 0, stream>>>(features, W1, iso, B, N);
    gather_agg<128, true><<<ga, 256, 0, stream>>>(B, row_ptr, col, isi, A, N);

    // --- layer 2 ---
    gemm_scaled<128><<<g128, 256, 0, stream>>>(A, W2, iso, B, N);
    gather_agg<128, true><<<ga, 256, 0, stream>>>(B, row_ptr, col, isi, A, N);

    // --- layer 3 ---
    gemm_scaled<64><<<g64, 256, 0, stream>>>(A, W3, iso, B, N);
    gather_agg<64, false><<<ga, 256, 0, stream>>>(B, row_ptr, col, isi, out, N);
}

// Round 3
// 996.064 us; speedup vs baseline: 7.3193x; 1.2114x over previous
//
#include <hip/hip_runtime.h>

// ---------------------------------------------------------------------------
// 3-layer GCN (DGL GraphConv norm='both') on MI355X.
// Round 3: (a) messages stored bf16 -> gather traffic halved;
//          (b) GEMM via split-bf16 MFMA (hi/lo x hi/lo, 3 products) ->
//              near-fp32 precision at MFMA speed, no LDS.
// ---------------------------------------------------------------------------

typedef float f32x4 __attribute__((ext_vector_type(4)));
typedef __bf16 bf16x8 __attribute__((ext_vector_type(8)));

__device__ inline unsigned short f2bf_bits(float f) {  // RNE
    unsigned u = __float_as_uint(f);
    unsigned r = u + 0x7fff + ((u >> 16) & 1);
    return (unsigned short)(r >> 16);
}
__device__ inline float bf_bits2f(unsigned short s) {
    return __uint_as_float(((unsigned)s) << 16);
}

// ---------------- CSR build + norms ----------------

__global__ __launch_bounds__(256) void count_kernel(
    const int* __restrict__ src, const int* __restrict__ dst,
    int* __restrict__ cnt_out, int* __restrict__ cnt_in, int E) {
    int e = blockIdx.x * 256 + threadIdx.x;
    if (e < E) {
        atomicAdd(&cnt_out[src[e]], 1);
        atomicAdd(&cnt_in[dst[e]], 1);
    }
}

__global__ __launch_bounds__(256) void invsqrt_kernel(
    const int* __restrict__ cnt_out, const int* __restrict__ cnt_in,
    float* __restrict__ iso, float* __restrict__ isi, int N) {
    int n = blockIdx.x * 256 + threadIdx.x;
    if (n < N) {
        float a = (float)cnt_out[n], b = (float)cnt_in[n];
        iso[n] = (a > 0.0f) ? rsqrtf(a) : 0.0f;
        isi[n] = (b > 0.0f) ? rsqrtf(b) : 0.0f;
    }
}

__global__ __launch_bounds__(1024) void scan_kernel(
    const int* __restrict__ cnt, int* __restrict__ row_ptr, int N) {
    __shared__ int sums[1024];
    const int tid = threadIdx.x;
    const int chunk = (N + 1023) / 1024;
    const int begin = tid * chunk;
    const int stop = min(begin + chunk, N);
    int s = 0;
    for (int i = begin; i < stop; ++i) s += cnt[i];
    sums[tid] = s;
    __syncthreads();
    for (int off = 1; off < 1024; off <<= 1) {
        int v = (tid >= off) ? sums[tid - off] : 0;
        __syncthreads();
        sums[tid] += v;
        __syncthreads();
    }
    int run = (tid > 0) ? sums[tid - 1] : 0;
    for (int i = begin; i < stop; ++i) {
        row_ptr[i] = run;
        run += cnt[i];
    }
    if (tid == 1023) row_ptr[N] = sums[1023];
}

__global__ __launch_bounds__(256) void fill_csr_kernel(
    const int* __restrict__ src, const int* __restrict__ dst,
    const int* __restrict__ row_ptr, int* __restrict__ cur,
    int* __restrict__ col, int E) {
    int e = blockIdx.x * 256 + threadIdx.x;
    if (e < E) {
        int d = dst[e];
        int p = row_ptr[d] + atomicAdd(&cur[d], 1);
        col[p] = src[e];
    }
}

// ---------------- W pre-pack: fp32 [K=128][F] -> bf16 hi/lo planes [F][128] ----

__global__ __launch_bounds__(256) void wpack_kernel(
    const float* __restrict__ W, unsigned short* __restrict__ Wt_hi,
    unsigned short* __restrict__ Wt_lo, int F) {
    int t = blockIdx.x * 256 + threadIdx.x;  // t = n*128 + k
    if (t >= F * 128) return;
    int n = t >> 7, k = t & 127;
    float w = W[k * F + n];
    unsigned short hb = f2bf_bits(w);
    Wt_hi[t] = hb;
    Wt_lo[t] = f2bf_bits(w - bf_bits2f(hb));
}

// ---------------- GEMM: Y(bf16)[N x F] = (so .* X)[N x 128] @ W[128 x F] ----
// 4 waves/block, 32 rows/wave (2 m-tiles), all F cols/wave (F/16 n-tiles).
// Split bf16: x = xh + xl, w = wh + wl; acc += xh*wh + xl*wh + xh*wl.
// Verified 16x16x32 layouts: A[m=lane&15][k=quad*8+j]; C/D col=lane&15,
// row=quad*4+reg.

template <int F>
__global__ __launch_bounds__(256) void gemm_mfma(
    const float* __restrict__ X, const unsigned short* __restrict__ Wt_hi,
    const unsigned short* __restrict__ Wt_lo, const float* __restrict__ so,
    unsigned short* __restrict__ Y, int N) {
    constexpr int NT = F / 16;  // n-tiles per wave
    const int wave = threadIdx.x >> 6;
    const int lane = threadIdx.x & 63;
    const int r0 = blockIdx.x * 128 + wave * 32;
    const int l15 = lane & 15;
    const int quad = lane >> 4;

    const int rowA0 = min(r0 + l15, N - 1);
    const int rowA1 = min(r0 + 16 + l15, N - 1);
    const float s0 = so[rowA0];
    const float s1 = so[rowA1];
    const float* pX0 = X + (size_t)rowA0 * 128 + quad * 8;
    const float* pX1 = X + (size_t)rowA1 * 128 + quad * 8;

    f32x4 acc0[NT], acc1[NT];
    const f32x4 z = {0.f, 0.f, 0.f, 0.f};
#pragma unroll
    for (int t = 0; t < NT; ++t) { acc0[t] = z; acc1[t] = z; }

    union AB { bf16x8 v; unsigned short u[8]; };

#pragma unroll
    for (int s = 0; s < 4; ++s) {
        const int kb = s * 32;  // + quad*8 folded into pointers
        // B fragments (hi/lo) for all n-tiles
        AB bh[NT], bl[NT];
#pragma unroll
        for (int t = 0; t < NT; ++t) {
            const int n = t * 16 + l15;
            bh[t].v = *(const bf16x8*)(Wt_hi + n * 128 + kb + quad * 8);
            bl[t].v = *(const bf16x8*)(Wt_lo + n * 128 + kb + quad * 8);
        }
        // A fragments, m-tile 0
        float a[8];
        *(f32x4*)&a[0] = *(const f32x4*)(pX0 + kb);
        *(f32x4*)&a[4] = *(const f32x4*)(pX0 + kb + 4);
        AB ah, al;
#pragma unroll
        for (int j = 0; j < 8; ++j) {
            float x = a[j] * s0;
            unsigned short hb = f2bf_bits(x);
            ah.u[j] = hb;
            al.u[j] = f2bf_bits(x - bf_bits2f(hb));
        }
#pragma unroll
        for (int t = 0; t < NT; ++t) {
            acc0[t] = __builtin_amdgcn_mfma_f32_16x16x32_bf16(ah.v, bh[t].v, acc0[t], 0, 0, 0);
            acc0[t] = __builtin_amdgcn_mfma_f32_16x16x32_bf16(al.v, bh[t].v, acc0[t], 0, 0, 0);
            acc0[t] = __builtin_amdgcn_mfma_f32_16x16x32_bf16(ah.v, bl[t].v, acc0[t], 0, 0, 0);
        }
        // A fragments, m-tile 1
        *(f32x4*)&a[0] = *(const f32x4*)(pX1 + kb);
        *(f32x4*)&a[4] = *(const f32x4*)(pX1 + kb + 4);
#pragma unroll
        for (int j = 0; j < 8; ++j) {
            float x = a[j] * s1;
            unsigned short hb = f2bf_bits(x);
            ah.u[j] = hb;
            al.u[j] = f2bf_bits(x - bf_bits2f(hb));
        }
#pragma unroll
        for (int t = 0; t < NT; ++t) {
            acc1[t] = __builtin_amdgcn_mfma_f32_16x16x32_bf16(ah.v, bh[t].v, acc1[t], 0, 0, 0);
            acc1[t] = __builtin_amdgcn_mfma_f32_16x16x32_bf16(al.v, bh[t].v, acc1[t], 0, 0, 0);
            acc1[t] = __builtin_amdgcn_mfma_f32_16x16x32_bf16(ah.v, bl[t].v, acc1[t], 0, 0, 0);
        }
    }

    // epilogue: C/D row = quad*4 + reg, col = l15
#pragma unroll
    for (int t = 0; t < NT; ++t) {
#pragma unroll
        for (int r = 0; r < 4; ++r) {
            int node0 = r0 + quad * 4 + r;
            if (node0 < N) Y[(size_t)node0 * F + t * 16 + l15] = f2bf_bits(acc0[t][r]);
            int node1 = r0 + 16 + quad * 4 + r;
            if (node1 < N) Y[(size_t)node1 * F + t * 16 + l15] = f2bf_bits(acc1[t][r]);
        }
    }
}

// ---------------- Pull aggregation over bf16 messages ----------------

template <bool RELU>
__global__ __launch_bounds__(256) void gather128(
    const unsigned short* __restrict__ msg, const int* __restrict__ row_ptr,
    const int* __restrict__ col, const float* __restrict__ isi,
    float* __restrict__ out, int N) {
    const int wave = (blockIdx.x * 256 + threadIdx.x) >> 6;
    const int lane = threadIdx.x & 63;
    if (wave >= N) return;
    const int start = row_ptr[wave], end = row_ptr[wave + 1];
    float a0 = 0.f, a1 = 0.f;
    for (int e = start; e < end; ++e) {
        const int c = col[e];  // wave-uniform
        const unsigned v = *(const unsigned*)(msg + (size_t)c * 128 + lane * 2);
        a0 += __uint_as_float(v << 16);
        a1 += __uint_as_float(v & 0xffff0000u);
    }
    const float sc = isi[wave];
    a0 *= sc; a1 *= sc;
    if (RELU) { a0 = fmaxf(a0, 0.f); a1 = fmaxf(a1, 0.f); }
    *(float2*)(out + (size_t)wave * 128 + lane * 2) = make_float2(a0, a1);
}

// F=64 final layer: 2 nodes per wave (half-wave each), fp32 output, no ReLU.
__global__ __launch_bounds__(256) void gather64(
    const unsigned short* __restrict__ msg, const int* __restrict__ row_ptr,
    const int* __restrict__ col, const float* __restrict__ isi,
    float* __restrict__ out, int N) {
    const int w = (blockIdx.x * 256 + threadIdx.x) >> 6;
    const int lane = threadIdx.x & 63;
    const int node = w * 2 + (lane >> 5);
    const int j = lane & 31;
    if (node >= N) return;
    const int start = row_ptr[node], end = row_ptr[node + 1];
    float a0 = 0.f, a1 = 0.f;
    for (int e = start; e < end; ++e) {
        const int c = col[e];  // uniform within half-wave
        const unsigned v = *(const unsigned*)(msg + (size_t)c * 64 + j * 2);
        a0 += __uint_as_float(v << 16);
        a1 += __uint_as_float(v & 0xffff0000u);
    }
    const float sc = isi[node];
    *(float2*)(out + (size_t)node * 64 + j * 2) = make_float2(a0 * sc, a1 * sc);
}

// ---------------- launch ----------------

extern "C" void kernel_launch(void* const* d_in, const int* in_sizes, int n_in,
                              void* d_out, int out_size, void* d_ws, size_t ws_size,
                              hipStream_t stream) {
    const float* features = (const float*)d_in[0];
    const float* W1 = (const float*)d_in[1];
    const float* W2 = (const float*)d_in[2];
    const float* W3 = (const float*)d_in[3];
    const int* src = (const int*)d_in[4];
    const int* dst = (const int*)d_in[5];
    float* out = (float*)d_out;

    const int N = in_sizes[0] / 128;  // 100000
    const int E = in_sizes[4];        // 1600000

    char* ws = (char*)d_ws;
    float* A = (float*)ws;                        ws += (size_t)N * 128 * 4;   // fp32 hidden
    unsigned short* Y = (unsigned short*)ws;      ws += (size_t)N * 128 * 2;   // bf16 messages
    int* cnt_out = (int*)ws;                      ws += (size_t)N * 4;
    int* cnt_in = (int*)ws;                       ws += (size_t)N * 4;
    int* row_ptr = (int*)ws;                      ws += (size_t)(N + 1) * 4;
    int* cur = (int*)ws;                          ws += (size_t)N * 4;
    int* col = (int*)ws;                          ws += (size_t)E * 4;
    float* iso = (float*)ws;                      ws += (size_t)N * 4;
    float* isi = (float*)ws;                      ws += (size_t)N * 4;
    unsigned short* Wt1h = (unsigned short*)ws;   ws += 128 * 128 * 2;
    unsigned short* Wt1l = (unsigned short*)ws;   ws += 128 * 128 * 2;
    unsigned short* Wt2h = (unsigned short*)ws;   ws += 128 * 128 * 2;
    unsigned short* Wt2l = (unsigned short*)ws;   ws += 128 * 128 * 2;
    unsigned short* Wt3h = (unsigned short*)ws;   ws += 64 * 128 * 2;
    unsigned short* Wt3l = (unsigned short*)ws;

    const int gE = (E + 255) / 256;
    const int gN = (N + 255) / 256;

    // W packing (tiny) + CSR build + norms
    wpack_kernel<<<(128 * 128 + 255) / 256, 256, 0, stream>>>(W1, Wt1h, Wt1l, 128);
    wpack_kernel<<<(128 * 128 + 255) / 256, 256, 0, stream>>>(W2, Wt2h, Wt2l, 128);
    wpack_kernel<<<(64 * 128 + 255) / 256, 256, 0, stream>>>(W3, Wt3h, Wt3l, 64);
    hipMemsetAsync(cnt_out, 0, 2 * (size_t)N * sizeof(int), stream);
    count_kernel<<<gE, 256, 0, stream>>>(src, dst, cnt_out, cnt_in, E);
    invsqrt_kernel<<<gN, 256, 0, stream>>>(cnt_out, cnt_in, iso, isi, N);
    scan_kernel<<<1, 1024, 0, stream>>>(cnt_in, row_ptr, N);
    hipMemsetAsync(cur, 0, (size_t)N * sizeof(int), stream);
    fill_csr_kernel<<<gE, 256, 0, stream>>>(src, dst, row_ptr, cur, col, E);

    const int gG = (N + 127) / 128;       // gemm grid: 128 rows/block
    const int ga128 = (N * 64 + 255) / 256;
    const int ga64 = ((N / 2 + 1) * 64 + 255) / 256;

    // layer 1
    gemm_mfma<128><<<gG, 256, 0, stream>>>(features, Wt1h, Wt1l, iso, Y, N);
    gather128<true><<<ga128, 256, 0, stream>>>(Y, row_ptr, col, isi, A, N);
    // layer 2
    gemm_mfma<128><<<gG, 256, 0, stream>>>(A, Wt2h, Wt2l, iso, Y, N);
    gather128<true><<<ga128, 256, 0, stream>>>(Y, row_ptr, col, isi, A, N);
    // layer 3
    gemm_mfma<64><<<gG, 256, 0, stream>>>(A, Wt3h, Wt3l, iso, Y, N);
    gather64<<<ga64, 256, 0, stream>>>(Y, row_ptr, col, isi, out, N);
}

// Round 4
// 848.890 us; speedup vs baseline: 8.5883x; 1.1734x over previous
//
#include <hip/hip_runtime.h>

// ---------------------------------------------------------------------------
// 3-layer GCN (DGL GraphConv norm='both') on MI355X.
// Round 4: replace single-block scan (163 us, 0.16% occupancy) with a
// 3-stage decomposed scan (~10 us). Rest unchanged from round 3:
// bf16 messages, split-bf16 MFMA GEMM, pull-CSR gather.
// ---------------------------------------------------------------------------

typedef float f32x4 __attribute__((ext_vector_type(4)));
typedef __bf16 bf16x8 __attribute__((ext_vector_type(8)));

__device__ inline unsigned short f2bf_bits(float f) {  // RNE
    unsigned u = __float_as_uint(f);
    unsigned r = u + 0x7fff + ((u >> 16) & 1);
    return (unsigned short)(r >> 16);
}
__device__ inline float bf_bits2f(unsigned short s) {
    return __uint_as_float(((unsigned)s) << 16);
}

// ---------------- CSR build + norms ----------------

__global__ __launch_bounds__(256) void count_kernel(
    const int* __restrict__ src, const int* __restrict__ dst,
    int* __restrict__ cnt_out, int* __restrict__ cnt_in, int E) {
    int e = blockIdx.x * 256 + threadIdx.x;
    if (e < E) {
        atomicAdd(&cnt_out[src[e]], 1);
        atomicAdd(&cnt_in[dst[e]], 1);
    }
}

__global__ __launch_bounds__(256) void invsqrt_kernel(
    const int* __restrict__ cnt_out, const int* __restrict__ cnt_in,
    float* __restrict__ iso, float* __restrict__ isi, int N) {
    int n = blockIdx.x * 256 + threadIdx.x;
    if (n < N) {
        float a = (float)cnt_out[n], b = (float)cnt_in[n];
        iso[n] = (a > 0.0f) ? rsqrtf(a) : 0.0f;
        isi[n] = (b > 0.0f) ? rsqrtf(b) : 0.0f;
    }
}

// --- decomposed exclusive scan: cnt[0..N) -> row_ptr[0..N] ---
// Stage 1: per-1024-chunk totals. Grid = nchunks (<=256), 256 thr/block.
__global__ __launch_bounds__(256) void scan_partial(
    const int* __restrict__ cnt, int* __restrict__ partials, int N) {
    __shared__ int red[256];
    const int tid = threadIdx.x;
    const int base = blockIdx.x * 1024;
    int s = 0;
#pragma unroll
    for (int j = 0; j < 4; ++j) {
        int i = base + tid + j * 256;
        if (i < N) s += cnt[i];
    }
    red[tid] = s;
    __syncthreads();
    for (int off = 128; off > 0; off >>= 1) {
        if (tid < off) red[tid] += red[tid + off];
        __syncthreads();
    }
    if (tid == 0) partials[blockIdx.x] = red[0];
}

// Stage 2: exclusive scan of partials (nparts <= 256), one block.
__global__ __launch_bounds__(256) void scan_base(
    const int* __restrict__ partials, int* __restrict__ chunk_base, int nparts) {
    __shared__ int s[256];
    const int tid = threadIdx.x;
    s[tid] = (tid < nparts) ? partials[tid] : 0;
    __syncthreads();
    for (int off = 1; off < 256; off <<= 1) {
        int v = (tid >= off) ? s[tid - off] : 0;
        __syncthreads();
        s[tid] += v;
        __syncthreads();
    }
    if (tid < nparts) chunk_base[tid] = (tid > 0) ? s[tid - 1] : 0;
}

// Stage 3: per-chunk exclusive scan + base; writes row_ptr (and row_ptr[N]).
__global__ __launch_bounds__(256) void scan_chunks(
    const int* __restrict__ cnt, const int* __restrict__ chunk_base,
    int* __restrict__ row_ptr, int N) {
    __shared__ int tsum[256];
    const int tid = threadIdx.x;
    const int base = blockIdx.x * 1024 + tid * 4;
    int v[4];
    int s = 0;
#pragma unroll
    for (int j = 0; j < 4; ++j) {
        int idx = base + j;
        v[j] = (idx < N) ? cnt[idx] : 0;
        s += v[j];
    }
    tsum[tid] = s;
    __syncthreads();
    for (int off = 1; off < 256; off <<= 1) {
        int t = (tid >= off) ? tsum[tid - off] : 0;
        __syncthreads();
        tsum[tid] += t;
        __syncthreads();
    }
    int run = chunk_base[blockIdx.x] + ((tid > 0) ? tsum[tid - 1] : 0);
#pragma unroll
    for (int j = 0; j < 4; ++j) {
        int idx = base + j;
        if (idx < N) row_ptr[idx] = run;
        run += v[j];
    }
    if ((int)blockIdx.x == (int)gridDim.x - 1 && tid == 255)
        row_ptr[N] = chunk_base[blockIdx.x] + tsum[255];
}

__global__ __launch_bounds__(256) void fill_csr_kernel(
    const int* __restrict__ src, const int* __restrict__ dst,
    const int* __restrict__ row_ptr, int* __restrict__ cur,
    int* __restrict__ col, int E) {
    int e = blockIdx.x * 256 + threadIdx.x;
    if (e < E) {
        int d = dst[e];
        int p = row_ptr[d] + atomicAdd(&cur[d], 1);
        col[p] = src[e];
    }
}

// ---------------- W pre-pack: fp32 [K=128][F] -> bf16 hi/lo planes [F][128] ----

__global__ __launch_bounds__(256) void wpack_kernel(
    const float* __restrict__ W, unsigned short* __restrict__ Wt_hi,
    unsigned short* __restrict__ Wt_lo, int F) {
    int t = blockIdx.x * 256 + threadIdx.x;  // t = n*128 + k
    if (t >= F * 128) return;
    int n = t >> 7, k = t & 127;
    float w = W[k * F + n];
    unsigned short hb = f2bf_bits(w);
    Wt_hi[t] = hb;
    Wt_lo[t] = f2bf_bits(w - bf_bits2f(hb));
}

// ---------------- GEMM: Y(bf16)[N x F] = (so .* X)[N x 128] @ W[128 x F] ----

template <int F>
__global__ __launch_bounds__(256) void gemm_mfma(
    const float* __restrict__ X, const unsigned short* __restrict__ Wt_hi,
    const unsigned short* __restrict__ Wt_lo, const float* __restrict__ so,
    unsigned short* __restrict__ Y, int N) {
    constexpr int NT = F / 16;  // n-tiles per wave
    const int wave = threadIdx.x >> 6;
    const int lane = threadIdx.x & 63;
    const int r0 = blockIdx.x * 128 + wave * 32;
    const int l15 = lane & 15;
    const int quad = lane >> 4;

    const int rowA0 = min(r0 + l15, N - 1);
    const int rowA1 = min(r0 + 16 + l15, N - 1);
    const float s0 = so[rowA0];
    const float s1 = so[rowA1];
    const float* pX0 = X + (size_t)rowA0 * 128 + quad * 8;
    const float* pX1 = X + (size_t)rowA1 * 128 + quad * 8;

    f32x4 acc0[NT], acc1[NT];
    const f32x4 z = {0.f, 0.f, 0.f, 0.f};
#pragma unroll
    for (int t = 0; t < NT; ++t) { acc0[t] = z; acc1[t] = z; }

    union AB { bf16x8 v; unsigned short u[8]; };

#pragma unroll
    for (int s = 0; s < 4; ++s) {
        const int kb = s * 32;
        AB bh[NT], bl[NT];
#pragma unroll
        for (int t = 0; t < NT; ++t) {
            const int n = t * 16 + l15;
            bh[t].v = *(const bf16x8*)(Wt_hi + n * 128 + kb + quad * 8);
            bl[t].v = *(const bf16x8*)(Wt_lo + n * 128 + kb + quad * 8);
        }
        float a[8];
        *(f32x4*)&a[0] = *(const f32x4*)(pX0 + kb);
        *(f32x4*)&a[4] = *(const f32x4*)(pX0 + kb + 4);
        AB ah, al;
#pragma unroll
        for (int j = 0; j < 8; ++j) {
            float x = a[j] * s0;
            unsigned short hb = f2bf_bits(x);
            ah.u[j] = hb;
            al.u[j] = f2bf_bits(x - bf_bits2f(hb));
        }
#pragma unroll
        for (int t = 0; t < NT; ++t) {
            acc0[t] = __builtin_amdgcn_mfma_f32_16x16x32_bf16(ah.v, bh[t].v, acc0[t], 0, 0, 0);
            acc0[t] = __builtin_amdgcn_mfma_f32_16x16x32_bf16(al.v, bh[t].v, acc0[t], 0, 0, 0);
            acc0[t] = __builtin_amdgcn_mfma_f32_16x16x32_bf16(ah.v, bl[t].v, acc0[t], 0, 0, 0);
        }
        *(f32x4*)&a[0] = *(const f32x4*)(pX1 + kb);
        *(f32x4*)&a[4] = *(const f32x4*)(pX1 + kb + 4);
#pragma unroll
        for (int j = 0; j < 8; ++j) {
            float x = a[j] * s1;
            unsigned short hb = f2bf_bits(x);
            ah.u[j] = hb;
            al.u[j] = f2bf_bits(x - bf_bits2f(hb));
        }
#pragma unroll
        for (int t = 0; t < NT; ++t) {
            acc1[t] = __builtin_amdgcn_mfma_f32_16x16x32_bf16(ah.v, bh[t].v, acc1[t], 0, 0, 0);
            acc1[t] = __builtin_amdgcn_mfma_f32_16x16x32_bf16(al.v, bh[t].v, acc1[t], 0, 0, 0);
            acc1[t] = __builtin_amdgcn_mfma_f32_16x16x32_bf16(ah.v, bl[t].v, acc1[t], 0, 0, 0);
        }
    }

#pragma unroll
    for (int t = 0; t < NT; ++t) {
#pragma unroll
        for (int r = 0; r < 4; ++r) {
            int node0 = r0 + quad * 4 + r;
            if (node0 < N) Y[(size_t)node0 * F + t * 16 + l15] = f2bf_bits(acc0[t][r]);
            int node1 = r0 + 16 + quad * 4 + r;
            if (node1 < N) Y[(size_t)node1 * F + t * 16 + l15] = f2bf_bits(acc1[t][r]);
        }
    }
}

// ---------------- Pull aggregation over bf16 messages ----------------

template <bool RELU>
__global__ __launch_bounds__(256) void gather128(
    const unsigned short* __restrict__ msg, const int* __restrict__ row_ptr,
    const int* __restrict__ col, const float* __restrict__ isi,
    float* __restrict__ out, int N) {
    const int wave = (blockIdx.x * 256 + threadIdx.x) >> 6;
    const int lane = threadIdx.x & 63;
    if (wave >= N) return;
    const int start = row_ptr[wave], end = row_ptr[wave + 1];
    float a0 = 0.f, a1 = 0.f;
    for (int e = start; e < end; ++e) {
        const int c = col[e];  // wave-uniform
        const unsigned v = *(const unsigned*)(msg + (size_t)c * 128 + lane * 2);
        a0 += __uint_as_float(v << 16);
        a1 += __uint_as_float(v & 0xffff0000u);
    }
    const float sc = isi[wave];
    a0 *= sc; a1 *= sc;
    if (RELU) { a0 = fmaxf(a0, 0.f); a1 = fmaxf(a1, 0.f); }
    *(float2*)(out + (size_t)wave * 128 + lane * 2) = make_float2(a0, a1);
}

__global__ __launch_bounds__(256) void gather64(
    const unsigned short* __restrict__ msg, const int* __restrict__ row_ptr,
    const int* __restrict__ col, const float* __restrict__ isi,
    float* __restrict__ out, int N) {
    const int w = (blockIdx.x * 256 + threadIdx.x) >> 6;
    const int lane = threadIdx.x & 63;
    const int node = w * 2 + (lane >> 5);
    const int j = lane & 31;
    if (node >= N) return;
    const int start = row_ptr[node], end = row_ptr[node + 1];
    float a0 = 0.f, a1 = 0.f;
    for (int e = start; e < end; ++e) {
        const int c = col[e];  // uniform within half-wave
        const unsigned v = *(const unsigned*)(msg + (size_t)c * 64 + j * 2);
        a0 += __uint_as_float(v << 16);
        a1 += __uint_as_float(v & 0xffff0000u);
    }
    const float sc = isi[node];
    *(float2*)(out + (size_t)node * 64 + j * 2) = make_float2(a0 * sc, a1 * sc);
}

// ---------------- launch ----------------

extern "C" void kernel_launch(void* const* d_in, const int* in_sizes, int n_in,
                              void* d_out, int out_size, void* d_ws, size_t ws_size,
                              hipStream_t stream) {
    const float* features = (const float*)d_in[0];
    const float* W1 = (const float*)d_in[1];
    const float* W2 = (const float*)d_in[2];
    const float* W3 = (const float*)d_in[3];
    const int* src = (const int*)d_in[4];
    const int* dst = (const int*)d_in[5];
    float* out = (float*)d_out;

    const int N = in_sizes[0] / 128;  // 100000
    const int E = in_sizes[4];        // 1600000

    char* ws = (char*)d_ws;
    float* A = (float*)ws;                        ws += (size_t)N * 128 * 4;   // fp32 hidden
    unsigned short* Y = (unsigned short*)ws;      ws += (size_t)N * 128 * 2;   // bf16 messages
    int* cnt_out = (int*)ws;                      ws += (size_t)N * 4;
    int* cnt_in = (int*)ws;                       ws += (size_t)N * 4;
    int* row_ptr = (int*)ws;                      ws += (size_t)(N + 1) * 4;
    int* cur = (int*)ws;                          ws += (size_t)N * 4;
    int* col = (int*)ws;                          ws += (size_t)E * 4;
    float* iso = (float*)ws;                      ws += (size_t)N * 4;
    float* isi = (float*)ws;                      ws += (size_t)N * 4;
    int* partials = (int*)ws;                     ws += 256 * 4;
    int* chunk_base = (int*)ws;                   ws += 256 * 4;
    unsigned short* Wt1h = (unsigned short*)ws;   ws += 128 * 128 * 2;
    unsigned short* Wt1l = (unsigned short*)ws;   ws += 128 * 128 * 2;
    unsigned short* Wt2h = (unsigned short*)ws;   ws += 128 * 128 * 2;
    unsigned short* Wt2l = (unsigned short*)ws;   ws += 128 * 128 * 2;
    unsigned short* Wt3h = (unsigned short*)ws;   ws += 64 * 128 * 2;
    unsigned short* Wt3l = (unsigned short*)ws;

    const int gE = (E + 255) / 256;
    const int gN = (N + 255) / 256;
    const int nchunks = (N + 1023) / 1024;  // 98 <= 256

    // W packing (tiny) + CSR build + norms
    wpack_kernel<<<(128 * 128 + 255) / 256, 256, 0, stream>>>(W1, Wt1h, Wt1l, 128);
    wpack_kernel<<<(128 * 128 + 255) / 256, 256, 0, stream>>>(W2, Wt2h, Wt2l, 128);
    wpack_kernel<<<(64 * 128 + 255) / 256, 256, 0, stream>>>(W3, Wt3h, Wt3l, 64);
    hipMemsetAsync(cnt_out, 0, 2 * (size_t)N * sizeof(int), stream);
    count_kernel<<<gE, 256, 0, stream>>>(src, dst, cnt_out, cnt_in, E);
    invsqrt_kernel<<<gN, 256, 0, stream>>>(cnt_out, cnt_in, iso, isi, N);
    scan_partial<<<nchunks, 256, 0, stream>>>(cnt_in, partials, N);
    scan_base<<<1, 256, 0, stream>>>(partials, chunk_base, nchunks);
    scan_chunks<<<nchunks, 256, 0, stream>>>(cnt_in, chunk_base, row_ptr, N);
    hipMemsetAsync(cur, 0, (size_t)N * sizeof(int), stream);
    fill_csr_kernel<<<gE, 256, 0, stream>>>(src, dst, row_ptr, cur, col, E);

    const int gG = (N + 127) / 128;
    const int ga128 = (N * 64 + 255) / 256;
    const int ga64 = ((N / 2 + 1) * 64 + 255) / 256;

    // layer 1
    gemm_mfma<128><<<gG, 256, 0, stream>>>(features, Wt1h, Wt1l, iso, Y, N);
    gather128<true><<<ga128, 256, 0, stream>>>(Y, row_ptr, col, isi, A, N);
    // layer 2
    gemm_mfma<128><<<gG, 256, 0, stream>>>(A, Wt2h, Wt2l, iso, Y, N);
    gather128<true><<<ga128, 256, 0, stream>>>(Y, row_ptr, col, isi, A, N);
    // layer 3
    gemm_mfma<64><<<gG, 256, 0, stream>>>(A, Wt3h, Wt3l, iso, Y, N);
    gather64<<<ga64, 256, 0, stream>>>(Y, row_ptr, col, isi, out, N);
}

// Round 5
// 606.110 us; speedup vs baseline: 12.0284x; 1.4006x over previous
//
#include <hip/hip_runtime.h>

// ---------------------------------------------------------------------------
// 3-layer GCN (DGL GraphConv norm='both') on MI355X.
// Round 5: gather edge-loop unrolled x8 (8 gathers in flight vs ~0.4 —
// the loop was latency-serialized: col s_load -> dependent gather -> add).
// Masked tail group removes the serial remainder. fill_csr consumes cnt_in
// as cursor (drops `cur` + its memset).
// ---------------------------------------------------------------------------

typedef float f32x4 __attribute__((ext_vector_type(4)));
typedef __bf16 bf16x8 __attribute__((ext_vector_type(8)));

__device__ inline unsigned short f2bf_bits(float f) {  // RNE
    unsigned u = __float_as_uint(f);
    unsigned r = u + 0x7fff + ((u >> 16) & 1);
    return (unsigned short)(r >> 16);
}
__device__ inline float bf_bits2f(unsigned short s) {
    return __uint_as_float(((unsigned)s) << 16);
}
__device__ inline float bf_lo(unsigned v) { return __uint_as_float(v << 16); }
__device__ inline float bf_hi(unsigned v) { return __uint_as_float(v & 0xffff0000u); }

// ---------------- CSR build + norms ----------------

__global__ __launch_bounds__(256) void count_kernel(
    const int* __restrict__ src, const int* __restrict__ dst,
    int* __restrict__ cnt_out, int* __restrict__ cnt_in, int E) {
    int e = blockIdx.x * 256 + threadIdx.x;
    if (e < E) {
        atomicAdd(&cnt_out[src[e]], 1);
        atomicAdd(&cnt_in[dst[e]], 1);
    }
}

__global__ __launch_bounds__(256) void invsqrt_kernel(
    const int* __restrict__ cnt_out, const int* __restrict__ cnt_in,
    float* __restrict__ iso, float* __restrict__ isi, int N) {
    int n = blockIdx.x * 256 + threadIdx.x;
    if (n < N) {
        float a = (float)cnt_out[n], b = (float)cnt_in[n];
        iso[n] = (a > 0.0f) ? rsqrtf(a) : 0.0f;
        isi[n] = (b > 0.0f) ? rsqrtf(b) : 0.0f;
    }
}

// --- decomposed exclusive scan: cnt[0..N) -> row_ptr[0..N] ---
__global__ __launch_bounds__(256) void scan_partial(
    const int* __restrict__ cnt, int* __restrict__ partials, int N) {
    __shared__ int red[256];
    const int tid = threadIdx.x;
    const int base = blockIdx.x * 1024;
    int s = 0;
#pragma unroll
    for (int j = 0; j < 4; ++j) {
        int i = base + tid + j * 256;
        if (i < N) s += cnt[i];
    }
    red[tid] = s;
    __syncthreads();
    for (int off = 128; off > 0; off >>= 1) {
        if (tid < off) red[tid] += red[tid + off];
        __syncthreads();
    }
    if (tid == 0) partials[blockIdx.x] = red[0];
}

__global__ __launch_bounds__(256) void scan_base(
    const int* __restrict__ partials, int* __restrict__ chunk_base, int nparts) {
    __shared__ int s[256];
    const int tid = threadIdx.x;
    s[tid] = (tid < nparts) ? partials[tid] : 0;
    __syncthreads();
    for (int off = 1; off < 256; off <<= 1) {
        int v = (tid >= off) ? s[tid - off] : 0;
        __syncthreads();
        s[tid] += v;
        __syncthreads();
    }
    if (tid < nparts) chunk_base[tid] = (tid > 0) ? s[tid - 1] : 0;
}

__global__ __launch_bounds__(256) void scan_chunks(
    const int* __restrict__ cnt, const int* __restrict__ chunk_base,
    int* __restrict__ row_ptr, int N) {
    __shared__ int tsum[256];
    const int tid = threadIdx.x;
    const int base = blockIdx.x * 1024 + tid * 4;
    int v[4];
    int s = 0;
#pragma unroll
    for (int j = 0; j < 4; ++j) {
        int idx = base + j;
        v[j] = (idx < N) ? cnt[idx] : 0;
        s += v[j];
    }
    tsum[tid] = s;
    __syncthreads();
    for (int off = 1; off < 256; off <<= 1) {
        int t = (tid >= off) ? tsum[tid - off] : 0;
        __syncthreads();
        tsum[tid] += t;
        __syncthreads();
    }
    int run = chunk_base[blockIdx.x] + ((tid > 0) ? tsum[tid - 1] : 0);
#pragma unroll
    for (int j = 0; j < 4; ++j) {
        int idx = base + j;
        if (idx < N) row_ptr[idx] = run;
        run += v[j];
    }
    if ((int)blockIdx.x == (int)gridDim.x - 1 && tid == 255)
        row_ptr[N] = chunk_base[blockIdx.x] + tsum[255];
}

// Consumes cnt_in as the per-row cursor (must run AFTER invsqrt + scan).
__global__ __launch_bounds__(256) void fill_csr_kernel(
    const int* __restrict__ src, const int* __restrict__ dst,
    const int* __restrict__ row_ptr, int* __restrict__ cnt_in,
    int* __restrict__ col, int E) {
    int e = blockIdx.x * 256 + threadIdx.x;
    if (e < E) {
        int d = dst[e];
        int p = row_ptr[d] + atomicSub(&cnt_in[d], 1) - 1;
        col[p] = src[e];
    }
}

// ---------------- W pre-pack: fp32 [K=128][F] -> bf16 hi/lo planes [F][128] ----

__global__ __launch_bounds__(256) void wpack_kernel(
    const float* __restrict__ W, unsigned short* __restrict__ Wt_hi,
    unsigned short* __restrict__ Wt_lo, int F) {
    int t = blockIdx.x * 256 + threadIdx.x;  // t = n*128 + k
    if (t >= F * 128) return;
    int n = t >> 7, k = t & 127;
    float w = W[k * F + n];
    unsigned short hb = f2bf_bits(w);
    Wt_hi[t] = hb;
    Wt_lo[t] = f2bf_bits(w - bf_bits2f(hb));
}

// ---------------- GEMM: Y(bf16)[N x F] = (so .* X)[N x 128] @ W[128 x F] ----

template <int F>
__global__ __launch_bounds__(256) void gemm_mfma(
    const float* __restrict__ X, const unsigned short* __restrict__ Wt_hi,
    const unsigned short* __restrict__ Wt_lo, const float* __restrict__ so,
    unsigned short* __restrict__ Y, int N) {
    constexpr int NT = F / 16;  // n-tiles per wave
    const int wave = threadIdx.x >> 6;
    const int lane = threadIdx.x & 63;
    const int r0 = blockIdx.x * 128 + wave * 32;
    const int l15 = lane & 15;
    const int quad = lane >> 4;

    const int rowA0 = min(r0 + l15, N - 1);
    const int rowA1 = min(r0 + 16 + l15, N - 1);
    const float s0 = so[rowA0];
    const float s1 = so[rowA1];
    const float* pX0 = X + (size_t)rowA0 * 128 + quad * 8;
    const float* pX1 = X + (size_t)rowA1 * 128 + quad * 8;

    f32x4 acc0[NT], acc1[NT];
    const f32x4 z = {0.f, 0.f, 0.f, 0.f};
#pragma unroll
    for (int t = 0; t < NT; ++t) { acc0[t] = z; acc1[t] = z; }

    union AB { bf16x8 v; unsigned short u[8]; };

#pragma unroll
    for (int s = 0; s < 4; ++s) {
        const int kb = s * 32;
        AB bh[NT], bl[NT];
#pragma unroll
        for (int t = 0; t < NT; ++t) {
            const int n = t * 16 + l15;
            bh[t].v = *(const bf16x8*)(Wt_hi + n * 128 + kb + quad * 8);
            bl[t].v = *(const bf16x8*)(Wt_lo + n * 128 + kb + quad * 8);
        }
        float a[8];
        *(f32x4*)&a[0] = *(const f32x4*)(pX0 + kb);
        *(f32x4*)&a[4] = *(const f32x4*)(pX0 + kb + 4);
        AB ah, al;
#pragma unroll
        for (int j = 0; j < 8; ++j) {
            float x = a[j] * s0;
            unsigned short hb = f2bf_bits(x);
            ah.u[j] = hb;
            al.u[j] = f2bf_bits(x - bf_bits2f(hb));
        }
#pragma unroll
        for (int t = 0; t < NT; ++t) {
            acc0[t] = __builtin_amdgcn_mfma_f32_16x16x32_bf16(ah.v, bh[t].v, acc0[t], 0, 0, 0);
            acc0[t] = __builtin_amdgcn_mfma_f32_16x16x32_bf16(al.v, bh[t].v, acc0[t], 0, 0, 0);
            acc0[t] = __builtin_amdgcn_mfma_f32_16x16x32_bf16(ah.v, bl[t].v, acc0[t], 0, 0, 0);
        }
        *(f32x4*)&a[0] = *(const f32x4*)(pX1 + kb);
        *(f32x4*)&a[4] = *(const f32x4*)(pX1 + kb + 4);
#pragma unroll
        for (int j = 0; j < 8; ++j) {
            float x = a[j] * s1;
            unsigned short hb = f2bf_bits(x);
            ah.u[j] = hb;
            al.u[j] = f2bf_bits(x - bf_bits2f(hb));
        }
#pragma unroll
        for (int t = 0; t < NT; ++t) {
            acc1[t] = __builtin_amdgcn_mfma_f32_16x16x32_bf16(ah.v, bh[t].v, acc1[t], 0, 0, 0);
            acc1[t] = __builtin_amdgcn_mfma_f32_16x16x32_bf16(al.v, bh[t].v, acc1[t], 0, 0, 0);
            acc1[t] = __builtin_amdgcn_mfma_f32_16x16x32_bf16(ah.v, bl[t].v, acc1[t], 0, 0, 0);
        }
    }

#pragma unroll
    for (int t = 0; t < NT; ++t) {
#pragma unroll
        for (int r = 0; r < 4; ++r) {
            int node0 = r0 + quad * 4 + r;
            if (node0 < N) Y[(size_t)node0 * F + t * 16 + l15] = f2bf_bits(acc0[t][r]);
            int node1 = r0 + 16 + quad * 4 + r;
            if (node1 < N) Y[(size_t)node1 * F + t * 16 + l15] = f2bf_bits(acc1[t][r]);
        }
    }
}

// ---------------- Pull aggregation over bf16 messages (unroll x8) ----------------

template <bool RELU>
__global__ __launch_bounds__(256) void gather128(
    const unsigned short* __restrict__ msg, const int* __restrict__ row_ptr,
    const int* __restrict__ col, const float* __restrict__ isi,
    float* __restrict__ out, int N) {
    const int wave = (blockIdx.x * 256 + threadIdx.x) >> 6;
    const int lane = threadIdx.x & 63;
    if (wave >= N) return;
    const int start = row_ptr[wave], end = row_ptr[wave + 1];
    const unsigned* m32 = (const unsigned*)msg;  // row stride 64 dwords

    float a0 = 0.f, a1 = 0.f, b0 = 0.f, b1 = 0.f;
    int e = start;
    const int nfull = (end - start) & ~7;
    const int efull = start + nfull;
    for (; e < efull; e += 8) {
        int c[8];
#pragma unroll
        for (int j = 0; j < 8; ++j) c[j] = col[e + j];  // uniform, contiguous
        unsigned v[8];
#pragma unroll
        for (int j = 0; j < 8; ++j) v[j] = m32[(size_t)c[j] * 64 + lane];
#pragma unroll
        for (int j = 0; j < 8; j += 2) {
            a0 += bf_lo(v[j]);     a1 += bf_hi(v[j]);
            b0 += bf_lo(v[j + 1]); b1 += bf_hi(v[j + 1]);
        }
    }
    const int rem = end - e;
    if (rem > 0) {
        int c[8];
#pragma unroll
        for (int j = 0; j < 8; ++j) c[j] = col[e + min(j, rem - 1)];
        unsigned v[8];
#pragma unroll
        for (int j = 0; j < 8; ++j) v[j] = m32[(size_t)c[j] * 64 + lane];
#pragma unroll
        for (int j = 0; j < 8; ++j) {
            float x0 = (j < rem) ? bf_lo(v[j]) : 0.f;
            float x1 = (j < rem) ? bf_hi(v[j]) : 0.f;
            a0 += x0; a1 += x1;
        }
    }
    const float sc = isi[wave];
    a0 = (a0 + b0) * sc;
    a1 = (a1 + b1) * sc;
    if (RELU) { a0 = fmaxf(a0, 0.f); a1 = fmaxf(a1, 0.f); }
    *(float2*)(out + (size_t)wave * 128 + lane * 2) = make_float2(a0, a1);
}

// F=64 final layer: 2 nodes per wave (half-wave each), fp32 out, no ReLU.
__global__ __launch_bounds__(256) void gather64(
    const unsigned short* __restrict__ msg, const int* __restrict__ row_ptr,
    const int* __restrict__ col, const float* __restrict__ isi,
    float* __restrict__ out, int N) {
    const int w = (blockIdx.x * 256 + threadIdx.x) >> 6;
    const int lane = threadIdx.x & 63;
    const int node = w * 2 + (lane >> 5);
    const int j31 = lane & 31;
    if (node >= N) return;
    const int start = row_ptr[node], end = row_ptr[node + 1];
    const unsigned* m32 = (const unsigned*)msg;  // row stride 32 dwords

    float a0 = 0.f, a1 = 0.f, b0 = 0.f, b1 = 0.f;
    int e = start;
    const int nfull = (end - start) & ~7;
    const int efull = start + nfull;
    for (; e < efull; e += 8) {
        int c[8];
#pragma unroll
        for (int j = 0; j < 8; ++j) c[j] = col[e + j];
        unsigned v[8];
#pragma unroll
        for (int j = 0; j < 8; ++j) v[j] = m32[(size_t)c[j] * 32 + j31];
#pragma unroll
        for (int j = 0; j < 8; j += 2) {
            a0 += bf_lo(v[j]);     a1 += bf_hi(v[j]);
            b0 += bf_lo(v[j + 1]); b1 += bf_hi(v[j + 1]);
        }
    }
    const int rem = end - e;
    if (rem > 0) {
        int c[8];
#pragma unroll
        for (int j = 0; j < 8; ++j) c[j] = col[e + min(j, rem - 1)];
        unsigned v[8];
#pragma unroll
        for (int j = 0; j < 8; ++j) v[j] = m32[(size_t)c[j] * 32 + j31];
#pragma unroll
        for (int j = 0; j < 8; ++j) {
            float x0 = (j < rem) ? bf_lo(v[j]) : 0.f;
            float x1 = (j < rem) ? bf_hi(v[j]) : 0.f;
            a0 += x0; a1 += x1;
        }
    }
    const float sc = isi[node];
    *(float2*)(out + (size_t)node * 64 + j31 * 2) =
        make_float2((a0 + b0) * sc, (a1 + b1) * sc);
}

// ---------------- launch ----------------

extern "C" void kernel_launch(void* const* d_in, const int* in_sizes, int n_in,
                              void* d_out, int out_size, void* d_ws, size_t ws_size,
                              hipStream_t stream) {
    const float* features = (const float*)d_in[0];
    const float* W1 = (const float*)d_in[1];
    const float* W2 = (const float*)d_in[2];
    const float* W3 = (const float*)d_in[3];
    const int* src = (const int*)d_in[4];
    const int* dst = (const int*)d_in[5];
    float* out = (float*)d_out;

    const int N = in_sizes[0] / 128;  // 100000
    const int E = in_sizes[4];        // 1600000

    char* ws = (char*)d_ws;
    float* A = (float*)ws;                        ws += (size_t)N * 128 * 4;   // fp32 hidden
    unsigned short* Y = (unsigned short*)ws;      ws += (size_t)N * 128 * 2;   // bf16 messages
    int* cnt_out = (int*)ws;                      ws += (size_t)N * 4;
    int* cnt_in = (int*)ws;                       ws += (size_t)N * 4;
    int* row_ptr = (int*)ws;                      ws += (size_t)(N + 1) * 4;
    int* col = (int*)ws;                          ws += (size_t)E * 4;
    float* iso = (float*)ws;                      ws += (size_t)N * 4;
    float* isi = (float*)ws;                      ws += (size_t)N * 4;
    int* partials = (int*)ws;                     ws += 256 * 4;
    int* chunk_base = (int*)ws;                   ws += 256 * 4;
    unsigned short* Wt1h = (unsigned short*)ws;   ws += 128 * 128 * 2;
    unsigned short* Wt1l = (unsigned short*)ws;   ws += 128 * 128 * 2;
    unsigned short* Wt2h = (unsigned short*)ws;   ws += 128 * 128 * 2;
    unsigned short* Wt2l = (unsigned short*)ws;   ws += 128 * 128 * 2;
    unsigned short* Wt3h = (unsigned short*)ws;   ws += 64 * 128 * 2;
    unsigned short* Wt3l = (unsigned short*)ws;

    const int gE = (E + 255) / 256;
    const int gN = (N + 255) / 256;
    const int nchunks = (N + 1023) / 1024;  // 98 <= 256

    wpack_kernel<<<(128 * 128 + 255) / 256, 256, 0, stream>>>(W1, Wt1h, Wt1l, 128);
    wpack_kernel<<<(128 * 128 + 255) / 256, 256, 0, stream>>>(W2, Wt2h, Wt2l, 128);
    wpack_kernel<<<(64 * 128 + 255) / 256, 256, 0, stream>>>(W3, Wt3h, Wt3l, 64);
    hipMemsetAsync(cnt_out, 0, 2 * (size_t)N * sizeof(int), stream);
    count_kernel<<<gE, 256, 0, stream>>>(src, dst, cnt_out, cnt_in, E);
    invsqrt_kernel<<<gN, 256, 0, stream>>>(cnt_out, cnt_in, iso, isi, N);
    scan_partial<<<nchunks, 256, 0, stream>>>(cnt_in, partials, N);
    scan_base<<<1, 256, 0, stream>>>(partials, chunk_base, nchunks);
    scan_chunks<<<nchunks, 256, 0, stream>>>(cnt_in, chunk_base, row_ptr, N);
    fill_csr_kernel<<<gE, 256, 0, stream>>>(src, dst, row_ptr, cnt_in, col, E);

    const int gG = (N + 127) / 128;
    const int ga128 = (N * 64 + 255) / 256;
    const int ga64 = ((N / 2 + 1) * 64 + 255) / 256;

    // layer 1
    gemm_mfma<128><<<gG, 256, 0, stream>>>(features, Wt1h, Wt1l, iso, Y, N);
    gather128<true><<<ga128, 256, 0, stream>>>(Y, row_ptr, col, isi, A, N);
    // layer 2
    gemm_mfma<128><<<gG, 256, 0, stream>>>(A, Wt2h, Wt2l, iso, Y, N);
    gather128<true><<<ga128, 256, 0, stream>>>(Y, row_ptr, col, isi, A, N);
    // layer 3
    gemm_mfma<64><<<gG, 256, 0, stream>>>(A, Wt3h, Wt3l, iso, Y, N);
    gather64<<<ga64, 256, 0, stream>>>(Y, row_ptr, col, isi, out, N);
}